// Round 9
// baseline (328.110 us; speedup 1.0000x reference)
//
#include <hip/hip_runtime.h>
#include <hip/hip_bf16.h>
#include <math.h>

// Top-p + exponential-minimum sampling — single pass over logits.
//   - sort by prob desc == sort by logit desc
//   - kept == { (l,idx) >= (lcut,icut) } via descending exp-mass crossing
//   - argmin -log(xi)/p == argmin [ key[v] - l ],  key = log(-log(xi))
// N(0,1) logits => cutoff logit concentrates at lambda* = -0.2816 +- 0.02.
// Fixed window [WLO, WHI) = [-0.40625, -0.15625) covers the boundary with
// p ~ 1-1e-9 per row; all misses handled by an exact in-kernel fallback.
//   KD: fill out with NEG_FILL (no deps, launched first)
//   K0: key[v] = log(-log(xi[v])); compact candidates {key < -3} per slice seg
//   K1: 8 blocks/row: one streamed read: fp64 total & above-window mass, lmax,
//       window-token stash -> global, candidate argmin for l >= WHI
//   K2: 1 block/row: fixed-point (2^-32, integer-exact) 64-bin window masses,
//       boundary bin, rank-sort, crossing -> (lcut,icut); kept-window argmin
//       with key[] lookup; proof best < -3 - lmax; fallbacks; poke POS_FILL.

constexpr int   SLICES   = 8;
constexpr int   STCAP    = 2048;   // window-token stash per slice (mean ~1540)
constexpr int   CCAP     = 1024;   // candidates per slice segment (mean ~780)
constexpr int   WBINS    = 64;
constexpr float WLO      = -0.40625f;
constexpr float WHI      = -0.15625f;
constexpr float WSCALE   = 256.0f;
constexpr int   BINB_CAP = 768;    // boundary-bin tokens (mean ~192)
constexpr float CAND_THR = -3.0f;
constexpr float NEG_FILL = -100000.0f;
constexpr float POS_FILL =  100000.0f;
constexpr float TOPP     = 0.9f;
// fallback 4096-bin grid (round-7 math)
constexpr int   NBINS    = 4096;
constexpr float BIN_MIN  = -8.0f;
constexpr float BIN_SCALE= 256.0f;
constexpr float BIN_OFF  = 2048.0f;
constexpr float BIN_W    = 1.0f / 256.0f;

struct Ws {
    float*    key;      // [V]
    uint2*    cand;     // [SLICES*CCAP] (idx, key bits)
    int*      candCnt;  // [SLICES]
    uint2*    stash;    // [B*SLICES*STCAP] (l bits, idx)
    int*      stashCnt; // [B*SLICES]
    double*   totArr;   // [B*SLICES]
    double*   abvArr;   // [B*SLICES]
    float*    lmaxArr;  // [B*SLICES]
    unsigned long long* sliceBest; // [B*SLICES]
};

__device__ __forceinline__ unsigned sortable(float f) {
    unsigned u = __float_as_uint(f);
    return (u & 0x80000000u) ? ~u : (u | 0x80000000u);
}
__device__ __forceinline__ unsigned long long fxmass(float l) {
    return (unsigned long long)((double)__expf(l) * 4294967296.0);
}
__device__ __forceinline__ int binOf(float l) {
    int b = (int)fmaf(l, BIN_SCALE, BIN_OFF);
    return min(max(b, 0), NBINS - 1);
}

// ---------------- KD: NEG_FILL the output ----------------
__global__ __launch_bounds__(256)
void kd_neg(float4* __restrict__ out4, long total4)
{
    const long stride = (long)gridDim.x * 256;
    const float4 nf = make_float4(NEG_FILL, NEG_FILL, NEG_FILL, NEG_FILL);
    for (long i = (long)blockIdx.x * 256 + threadIdx.x; i < total4; i += stride)
        out4[i] = nf;
}

// ---------------- K0: keys + per-segment candidate lists ----------------
__global__ __launch_bounds__(1024)
void k0_keys(const float4* __restrict__ xi4, float* __restrict__ key,
             uint2* __restrict__ cand, int* __restrict__ candCnt, int V)
{
    const int seg = blockIdx.x;
    const int st4 = (V / SLICES) >> 2;
    const int base4 = seg * st4;
    __shared__ int cnt;
    __shared__ uint2 cl[CCAP];
    if (threadIdx.x == 0) cnt = 0;
    __syncthreads();

    for (int i = threadIdx.x; i < st4; i += 1024) {
        float4 x = xi4[base4 + i];
        float kv[4];
        kv[0] = __logf(-__logf(x.x));
        kv[1] = __logf(-__logf(x.y));
        kv[2] = __logf(-__logf(x.z));
        kv[3] = __logf(-__logf(x.w));
        reinterpret_cast<float4*>(key)[base4 + i] =
            make_float4(kv[0], kv[1], kv[2], kv[3]);
        #pragma unroll
        for (int c = 0; c < 4; ++c) {
            if (kv[c] < CAND_THR) {
                int p = atomicAdd(&cnt, 1);
                if (p < CCAP)
                    cl[p] = make_uint2((unsigned)((base4 + i) * 4 + c),
                                       __float_as_uint(kv[c]));
            }
        }
    }
    __syncthreads();
    const int n = min(cnt, CCAP);
    for (int i = threadIdx.x; i < CCAP; i += 1024)
        cand[seg * CCAP + i] = (i < n) ? cl[i] : make_uint2(0u, 0x7f800000u);
    if (threadIdx.x == 0) candCnt[seg] = cnt;
}

// ---------------- K1: single streamed sweep ----------------
__global__ __launch_bounds__(256, 8)
void k1_sweep(const float* __restrict__ logits, Ws ws, int V)
{
    const int row = blockIdx.x / SLICES;
    const int sl  = blockIdx.x % SLICES;
    const int st4 = (V / SLICES) >> 2;
    const float* rowp = logits + (size_t)row * V;
    const float4* p4 = reinterpret_cast<const float4*>(rowp) + (size_t)sl * st4;
    const int gbase = sl * st4 * 4;

    __shared__ uint2 ss[STCAP];
    __shared__ int scnt;
    __shared__ double wrT[4], wrA[4];
    __shared__ float  wrL[4];
    __shared__ unsigned long long wrB[4];
    if (threadIdx.x == 0) scnt = 0;
    __syncthreads();

    double tot = 0.0, abv = 0.0;
    float lmax = -INFINITY;
    for (int j = threadIdx.x; j < st4; j += 256) {
        float4 r = p4[j];
        float lv[4] = {r.x, r.y, r.z, r.w};
        #pragma unroll
        for (int c = 0; c < 4; ++c) {
            float l = lv[c];
            float e = __expf(l);
            tot += (double)e;
            abv += (l >= WHI) ? (double)e : 0.0;
            lmax = fmaxf(lmax, l);
            if (l >= WLO && l < WHI) {
                int p = atomicAdd(&scnt, 1);
                if (p < STCAP)
                    ss[p] = make_uint2(__float_as_uint(l),
                                       (unsigned)(gbase + j * 4 + c));
            }
        }
    }

    // candidate argmin for definitely-kept region (l >= WHI); own segment is L2-hot
    unsigned long long best = ~0ull;
    const int cn = min(ws.candCnt[sl], CCAP);
    const uint2* cl = ws.cand + sl * CCAP;
    for (int i = threadIdx.x; i < cn; i += 256) {
        uint2 c = cl[i];
        float l = rowp[c.x];
        if (l >= WHI) {
            float sc = __uint_as_float(c.y) - l;
            unsigned long long pack =
                ((unsigned long long)sortable(sc) << 32) | c.x;
            best = pack < best ? pack : best;
        }
    }
    __syncthreads();

    // flush stash
    const int n = min(scnt, STCAP);
    uint2* dst = ws.stash + ((size_t)row * SLICES + sl) * STCAP;
    for (int i = threadIdx.x; i < n; i += 256) dst[i] = ss[i];

    // block reductions (4 waves)
    for (int off = 32; off >= 1; off >>= 1) {
        tot += __shfl_down(tot, off);
        abv += __shfl_down(abv, off);
        lmax = fmaxf(lmax, __shfl_down(lmax, off));
        unsigned long long o = __shfl_down(best, off);
        best = o < best ? o : best;
    }
    const int wv = threadIdx.x >> 6;
    if ((threadIdx.x & 63) == 0) {
        wrT[wv] = tot; wrA[wv] = abv; wrL[wv] = lmax; wrB[wv] = best;
    }
    __syncthreads();
    if (threadIdx.x == 0) {
        double T = 0.0, A = 0.0; float L = -INFINITY;
        unsigned long long Bt = ~0ull;
        for (int w = 0; w < 4; ++w) {
            T += wrT[w]; A += wrA[w]; L = fmaxf(L, wrL[w]);
            Bt = wrB[w] < Bt ? wrB[w] : Bt;
        }
        const int s = row * SLICES + sl;
        ws.totArr[s] = T; ws.abvArr[s] = A; ws.lmaxArr[s] = L;
        ws.sliceBest[s] = Bt; ws.stashCnt[s] = scnt;
    }
}

// ---------------- fallback scan helper (wave 0) -----------
__device__ __forceinline__ void scan_bins(const unsigned* lh, int lane,
                                          int& candBin, double& candS, double& target)
{
    const int hi = NBINS - 1 - (lane << 6);
    double seg = 0.0;
    for (int k = 0; k < 64; ++k) {
        int b = hi - k;
        seg += (double)lh[b] * (double)__expf(fmaf((float)b + 0.5f, BIN_W, BIN_MIN));
    }
    double v = seg;
    for (int off = 1; off < 64; off <<= 1) {
        double u = __shfl_up(v, off);
        if (lane >= off) v += u;
    }
    double excl = v - seg;
    double total = __shfl(v, 63);
    target = TOPP * total;

    candBin = -1; candS = 0.0;
    double cum = excl;
    for (int k = 0; k < 64; ++k) {
        int b = hi - k;
        double h = (double)lh[b] * (double)__expf(fmaf((float)b + 0.5f, BIN_W, BIN_MIN));
        if (candBin < 0 && cum + h >= target) { candBin = b; candS = cum; }
        cum += h;
    }
    for (int off = 32; off >= 1; off >>= 1) {
        int    ob = __shfl_xor(candBin, off);
        double os = __shfl_xor(candS, off);
        if (ob > candBin) { candBin = ob; candS = os; }
    }
}

// ---------------- K2: per-row exact resolution ----------------
__global__ __launch_bounds__(1024)
void k2_resolve(const float* __restrict__ logits, float* __restrict__ out,
                Ws ws, int V)
{
    const int row = blockIdx.x;
    const int tid = threadIdx.x;
    const float* rowp = logits + (size_t)row * V;
    const float* key = ws.key;

    __shared__ unsigned long long massFx[WBINS];
    __shared__ float s_bl[BINB_CAP];
    __shared__ int   s_bi[BINB_CAP];
    __shared__ float s_sl[BINB_CAP];
    __shared__ int   s_si[BINB_CAP];
    __shared__ unsigned fbhist[NBINS];
    __shared__ unsigned long long wrd[16];
    __shared__ int   sB2, sB, sNeedB, sNeedA;
    __shared__ float sLcut, sLmax;
    __shared__ int   sIcut;
    __shared__ double sCumAboveB, sTarget;
    __shared__ unsigned long long sBestHi, sBest;

    // --- reduce per-slice stats ---
    if (tid == 0) {
        double T = 0.0, A = 0.0; float L = -INFINITY;
        unsigned long long Bt = ~0ull;
        int needB = 0, needA = 0;
        for (int k = 0; k < SLICES; ++k) {
            const int s = row * SLICES + k;
            T += ws.totArr[s]; A += ws.abvArr[s];
            L = fmaxf(L, ws.lmaxArr[s]);
            unsigned long long v = ws.sliceBest[s];
            Bt = v < Bt ? v : Bt;
            if (ws.stashCnt[s] > STCAP) needB = 1;
            if (ws.candCnt[k] > CCAP)   needA = 1;
        }
        sTarget = (double)TOPP * T;
        sLmax = L; sBestHi = Bt;
        sNeedB = needB; sNeedA = needA;
        sCumAboveB = A;      // temporarily: above-window mass
        sB2 = 0;
    }
    for (int i = tid; i < WBINS; i += 1024) massFx[i] = 0ull;
    __syncthreads();

    // --- pass A: fixed-point window-bin masses ---
    for (int k = 0; k < SLICES; ++k) {
        const int s = row * SLICES + k;
        const int n = min(ws.stashCnt[s], STCAP);
        const uint2* sp = ws.stash + (size_t)s * STCAP;
        for (int i = tid; i < n; i += 1024) {
            float l = __uint_as_float(sp[i].x);
            int wb = (int)floorf((l - WLO) * WSCALE);
            wb = min(max(wb, 0), WBINS - 1);
            atomicAdd(&massFx[wb], fxmass(l));
        }
    }
    __syncthreads();

    // --- find boundary bin B (serial, integer-exact masses) ---
    if (tid == 0) {
        double cum = sCumAboveB;          // above-window (fp64 from K1)
        const double target = sTarget;
        if (cum >= target) sNeedB = 1;
        else {
            int B = -1; double ca = 0.0;
            for (int b = WBINS - 1; b >= 0; --b) {
                double m = (double)massFx[b] * 0x1p-32;
                if (cum + m >= target) { B = b; ca = cum; break; }
                cum += m;
            }
            if (B < 0) sNeedB = 1;
            else { sB = B; sCumAboveB = ca; }
        }
    }
    __syncthreads();

    if (!sNeedB) {
        // --- pass B: gather bin-B tokens ---
        const int B = sB;
        for (int k = 0; k < SLICES; ++k) {
            const int s = row * SLICES + k;
            const int n = min(ws.stashCnt[s], STCAP);
            const uint2* sp = ws.stash + (size_t)s * STCAP;
            for (int i = tid; i < n; i += 1024) {
                float l = __uint_as_float(sp[i].x);
                int wb = (int)floorf((l - WLO) * WSCALE);
                wb = min(max(wb, 0), WBINS - 1);
                if (wb == B) {
                    int q = atomicAdd(&sB2, 1);
                    if (q < BINB_CAP) { s_bl[q] = l; s_bi[q] = (int)sp[i].y; }
                }
            }
        }
        __syncthreads();
        const int nB = min(sB2, BINB_CAP);
        if (sB2 > BINB_CAP && tid == 0) sNeedB = 1;
        __syncthreads();
        if (!sNeedB) {
            // rank-sort desc by (l, idx asc)
            for (int i = tid; i < nB; i += 1024) {
                float li = s_bl[i]; int ii = s_bi[i];
                int r = 0;
                for (int j = 0; j < nB; ++j) {
                    float lj = s_bl[j]; int ij = s_bi[j];
                    r += (lj > li) || (lj == li && ij < ii);
                }
                s_sl[r] = li; s_si[r] = ii;
            }
            __syncthreads();
            if (tid == 0) {
                double cum = sCumAboveB;
                const double target = sTarget;
                int m = nB;
                for (int k = 0; k < nB; ++k) {
                    cum += (double)fxmass(s_sl[k]) * 0x1p-32;
                    if (cum >= target) { m = k + 1; break; }
                }
                m = max(m, 1);
                sLcut = s_sl[m - 1];
                sIcut = s_si[m - 1];
            }
            __syncthreads();
        }
    }

    unsigned long long best = ~0ull;
    if (!sNeedB) {
        // --- pass C: exact argmin over kept window tokens ---
        const float lcut = sLcut; const int icut = sIcut;
        for (int k = 0; k < SLICES; ++k) {
            const int s = row * SLICES + k;
            const int n = min(ws.stashCnt[s], STCAP);
            const uint2* sp = ws.stash + (size_t)s * STCAP;
            for (int i = tid; i < n; i += 1024) {
                float l = __uint_as_float(sp[i].x);
                int idx = (int)sp[i].y;
                bool kept = (l > lcut) || (l == lcut && idx <= icut);
                if (kept) {
                    float sc = key[idx] - l;
                    unsigned long long pack =
                        ((unsigned long long)sortable(sc) << 32) | (unsigned)idx;
                    best = pack < best ? pack : best;
                }
            }
        }
        for (int off = 32; off >= 1; off >>= 1) {
            unsigned long long o = __shfl_down(best, off);
            best = o < best ? o : best;
        }
        if ((tid & 63) == 0) wrd[tid >> 6] = best;
        __syncthreads();
        if (tid == 0) {
            unsigned long long b = sBestHi;
            for (int w = 0; w < 16; ++w) b = wrd[w] < b ? wrd[w] : b;
            sBest = b;
            // proof: any non-candidate scores >= CAND_THR - lmax
            unsigned bound = sortable(CAND_THR - sLmax);
            if (!((unsigned)(b >> 32) < bound)) sNeedA = 1;
        }
        __syncthreads();
    }

    // --- fallback B: window missed -> full hist pass (round-7 math) ---
    if (sNeedB) {
        for (int i = tid; i < NBINS; i += 1024) fbhist[i] = 0u;
        if (tid == 0) sB2 = 0;
        __syncthreads();
        const int n4 = V >> 2;
        const float4* p4 = reinterpret_cast<const float4*>(rowp);
        for (int j = tid; j < n4; j += 1024) {
            float4 r = p4[j];
            atomicAdd(&fbhist[binOf(r.x)], 1u);
            atomicAdd(&fbhist[binOf(r.y)], 1u);
            atomicAdd(&fbhist[binOf(r.z)], 1u);
            atomicAdd(&fbhist[binOf(r.w)], 1u);
        }
        __syncthreads();
        if (tid < 64) {
            int b; double cs, tg;
            scan_bins(fbhist, tid, b, cs, tg);
            if (tid == 0) { sB = b; sCumAboveB = cs; sTarget = tg; }
        }
        __syncthreads();
        const int B = sB;
        for (int j = tid; j < V; j += 1024) {
            float l = rowp[j];
            if (binOf(l) == B) {
                int q = atomicAdd(&sB2, 1);
                if (q < BINB_CAP) { s_bl[q] = l; s_bi[q] = j; }
            }
        }
        __syncthreads();
        const int nB = min(sB2, BINB_CAP);
        for (int i = tid; i < nB; i += 1024) {
            float li = s_bl[i]; int ii = s_bi[i];
            int r = 0;
            for (int j = 0; j < nB; ++j) {
                float lj = s_bl[j]; int ij = s_bi[j];
                r += (lj > li) || (lj == li && ij < ii);
            }
            s_sl[r] = li; s_si[r] = ii;
        }
        __syncthreads();
        if (tid == 0) {
            double cum = sCumAboveB;
            const double target = sTarget;
            int m = nB;
            for (int k = 0; k < nB; ++k) {
                cum += (double)fxmass(s_sl[k]) * 0x1p-32;
                if (cum >= target) { m = k + 1; break; }
            }
            m = max(m, 1);
            if (nB == 0) { sLcut = (float)B * BIN_W + BIN_MIN; sIcut = 0x7fffffff; }
            else { sLcut = s_sl[m - 1]; sIcut = s_si[m - 1]; }
            sNeedA = 1;
        }
        __syncthreads();
    }

    // --- fallback A: exact full argmin sweep over kept ---
    if (sNeedA) {
        const float lcut = sLcut; const int icut = sIcut;
        unsigned long long fb = ~0ull;
        for (int j = tid; j < V; j += 1024) {
            float l = rowp[j];
            bool kept = (l > lcut) || (l == lcut && j <= icut);
            if (kept) {
                unsigned long long pack =
                    ((unsigned long long)sortable(key[j] - l) << 32) | (unsigned)j;
                fb = pack < fb ? pack : fb;
            }
        }
        for (int off = 32; off >= 1; off >>= 1) {
            unsigned long long o = __shfl_down(fb, off);
            fb = o < fb ? o : fb;
        }
        if ((tid & 63) == 0) wrd[tid >> 6] = fb;
        __syncthreads();
        if (tid == 0) {
            unsigned long long b = ~0ull;
            for (int w = 0; w < 16; ++w) b = wrd[w] < b ? wrd[w] : b;
            sBest = b;
        }
        __syncthreads();
    }

    if (tid == 0)
        out[(size_t)row * V + (unsigned)(sBest & 0xffffffffu)] = POS_FILL;
}

extern "C" void kernel_launch(void* const* d_in, const int* in_sizes, int n_in,
                              void* d_out, int out_size, void* d_ws, size_t ws_size,
                              hipStream_t stream) {
    // d_in[0] = input_ids (int64, unused)
    // d_in[1] = logits f32 [B, V]
    // d_in[2] = xi     f32 [V]
    const float* logits = (const float*)d_in[1];
    const float* xi     = (const float*)d_in[2];
    float*       out    = (float*)d_out;
    const int V = in_sizes[2];
    const int B = in_sizes[1] / V;

    char* w = (char*)d_ws;
    size_t off = 0;
    Ws ws;
    ws.key       = (float*)(w + off);  off += (size_t)V * sizeof(float);
    off = (off + 255) & ~(size_t)255;
    ws.cand      = (uint2*)(w + off);  off += (size_t)SLICES * CCAP * sizeof(uint2);
    ws.candCnt   = (int*)(w + off);    off += (size_t)SLICES * sizeof(int);
    off = (off + 255) & ~(size_t)255;
    ws.stash     = (uint2*)(w + off);  off += (size_t)B * SLICES * STCAP * sizeof(uint2);
    ws.stashCnt  = (int*)(w + off);    off += (size_t)B * SLICES * sizeof(int);
    off = (off + 255) & ~(size_t)255;
    ws.totArr    = (double*)(w + off); off += (size_t)B * SLICES * sizeof(double);
    ws.abvArr    = (double*)(w + off); off += (size_t)B * SLICES * sizeof(double);
    ws.lmaxArr   = (float*)(w + off);  off += (size_t)B * SLICES * sizeof(float);
    off = (off + 255) & ~(size_t)255;
    ws.sliceBest = (unsigned long long*)(w + off); off += (size_t)B * SLICES * sizeof(unsigned long long);

    const long total4 = (long)B * V / 4;
    kd_neg    <<<2048, 256, 0, stream>>>((float4*)out, total4);
    k0_keys   <<<SLICES, 1024, 0, stream>>>((const float4*)xi, ws.key,
                                            ws.cand, ws.candCnt, V);
    k1_sweep  <<<B * SLICES, 256, 0, stream>>>(logits, ws, V);
    k2_resolve<<<B, 1024, 0, stream>>>(logits, out, ws, V);
}